// Round 8
// baseline (785.478 us; speedup 1.0000x reference)
//
#include <hip/hip_runtime.h>

using half8 = __attribute__((ext_vector_type(8))) _Float16;
using f32x4 = __attribute__((ext_vector_type(4))) float;

__device__ __forceinline__ float sigmf(float x) {
    return __builtin_amdgcn_rcpf(1.0f + __expf(-x));
}
__device__ __forceinline__ float tanhx(float x) {
    return 1.0f - 2.0f * __builtin_amdgcn_rcpf(1.0f + __expf(x + x));
}

// ---------------------------------------------------------------------------
// Prep (one-time, parallel):
//  x16    : [75][112][76] fp16 (transposed x, zero-padded)
//  wihI0  : layer0 [512][76] fp16, row n = gate row (n&3)*128 + (n>>2)
//  wihP   : layers 1..5 plain [4H][HIN] fp16
//  whhP   : all layers plain [4H][H] fp16
//  biasI0 : layer0 summed bias, interleaved (matches wihI0 rows)
//  biasP  : layers 1..5 summed bias, plain [4H]
// ---------------------------------------------------------------------------
struct PrepPtrs {
    const float* wih[6];
    const float* whh[6];
    const float* bi[6];
    const float* bh[6];
    const float* x;
    _Float16* wihI0;
    _Float16* wihP[6];   // [0] unused
    _Float16* whhP[6];
    float* biasI0;
    float* biasP;        // L1@0, L2@512, L3@768, L4@1024, L5@1152
    _Float16* x16;
};

__global__ __launch_bounds__(256) void prep_kernel(PrepPtrs p) {
    int i = blockIdx.x * 256 + threadIdx.x;
    if (i < 642048) {  // x16: 8448 rows x 76
        int row = i / 76, k = i - row * 76;
        int t = row / 112, b = row - t * 112;
        float v = (b < 100 && k < 75 && t < 75)
                      ? p.x[((size_t)b * 75 + t) * 75 + k]
                      : 0.0f;
        p.x16[i] = (_Float16)v;
        return;
    }
    i -= 642048;
    if (i < 38912) {  // wihI0 [512][76]
        int n = i / 76, k = i - n * 76;
        int col = n >> 2, G = n & 3;
        float v = (k < 75) ? p.wih[0][(size_t)(G * 128 + col) * 75 + k] : 0.0f;
        p.wihI0[i] = (_Float16)v;
        return;
    }
    i -= 38912;
    constexpr int HH[6] = {128, 128, 64, 64, 32, 32};
    constexpr int II[6] = {75, 128, 128, 64, 64, 32};
    #pragma unroll
    for (int l = 1; l < 6; ++l) {  // plain wih
        int cnt = 4 * HH[l] * II[l];
        if (i < cnt) {
            p.wihP[l][i] = (_Float16)p.wih[l][i];
            return;
        }
        i -= cnt;
    }
    #pragma unroll
    for (int l = 0; l < 6; ++l) {  // plain whh
        int cnt = 4 * HH[l] * HH[l];
        if (i < cnt) {
            p.whhP[l][i] = (_Float16)p.whh[l][i];
            return;
        }
        i -= cnt;
    }
    if (i < 512) {  // biasI0 interleaved
        int col = i >> 2, G = i & 3;
        int src = G * 128 + col;
        p.biasI0[i] = p.bi[0][src] + p.bh[0][src];
        return;
    }
    i -= 512;
    constexpr int BOFF[6] = {0, 0, 512, 768, 1024, 1152};
    #pragma unroll
    for (int l = 1; l < 6; ++l) {  // biasP plain
        int cnt = 4 * HH[l];
        if (i < cnt) {
            p.biasP[BOFF[l] + i] = p.bi[l][i] + p.bh[l][i];
            return;
        }
        i -= cnt;
    }
}

// ---------------------------------------------------------------------------
// Layer-0 xg GEMM (unchanged from round 7): xg [75][28][512][4] f32;
// a lane's f32x4 at (n=col*4+G, bs0..3) is one MFMA C fragment.
// ---------------------------------------------------------------------------
template <int Ks>
__global__ __launch_bounds__(256) void gemm_xg(
    const _Float16* __restrict__ A, const _Float16* __restrict__ W,
    const float* __restrict__ bias, float* __restrict__ C, int Kv, int N) {
    constexpr int KP = Ks * 32;
    constexpr int LDK = KP + 8;
    __shared__ __align__(16) _Float16 Al[64][LDK];
    __shared__ __align__(16) _Float16 Wl[64][LDK];

    const int tid = threadIdx.x;
    const int tt = blockIdx.x >> 1;
    const int boff = (blockIdx.x & 1) * 48;
    const int n0 = blockIdx.y * 64;
    constexpr int HP = KP / 2;

    for (int idx = tid; idx < 64 * HP; idx += 256) {
        int row = idx / HP;
        int k = (idx - row * HP) * 2;
        unsigned int va = 0, vw = 0;
        if (k < Kv) {
            va = *(const unsigned int*)(A + (size_t)(tt * 112 + boff + row) * Kv + k);
            vw = *(const unsigned int*)(W + (size_t)(n0 + row) * Kv + k);
        }
        *(unsigned int*)&Al[row][k] = va;
        *(unsigned int*)&Wl[row][k] = vw;
    }
    __syncthreads();

    const int w = tid >> 6, l = tid & 63, hi = l >> 4;
    half8 a[Ks];
    #pragma unroll
    for (int kk = 0; kk < Ks; ++kk)
        a[kk] = *(const half8*)&Al[w * 16 + (l & 15)][kk * 32 + hi * 8];

    f32x4 acc[4];
    #pragma unroll
    for (int jt = 0; jt < 4; ++jt) {
        acc[jt] = f32x4{0.f, 0.f, 0.f, 0.f};
        #pragma unroll
        for (int kk = 0; kk < Ks; ++kk) {
            half8 b = *(const half8*)&Wl[jt * 16 + (l & 15)][kk * 32 + hi * 8];
            acc[jt] = __builtin_amdgcn_mfma_f32_16x16x32_f16(a[kk], b, acc[jt], 0, 0, 0);
        }
    }

    const int bx = (boff >> 2) + w * 4 + hi;
    #pragma unroll
    for (int jt = 0; jt < 4; ++jt) {
        int n = n0 + jt * 16 + (l & 15);
        float bs = bias[n];
        f32x4 v = acc[jt];
        v[0] += bs; v[1] += bs; v[2] += bs; v[3] += bs;
        *(f32x4*)(C + ((size_t)(tt * 28 + bx) * N + n) * 4) = v;
    }
}

// ---------------------------------------------------------------------------
// Fused 6-layer pipelined LSTM. 150 blocks = 6 layers x 25 batch-groups.
// Layer l block consumes h^{l-1} from global (flag-gated, acquire/agent) and
// produces h^l (release-fenced every 2 steps). Layer 0 uses precomputed xg
// as MFMA C-init; layers 1..5 compute Wih*h MFMA on the fly (weights in
// registers). M-replication: A rows replicate 4 batch rows; each lane
// activates one h element (PICK by hi). Bounded spins: deadlock -> garbage,
// never a hang.
// ---------------------------------------------------------------------------
struct FusedPtrs {
    const _Float16* whh[6];
    const _Float16* wih[6];  // [0] unused
    const float* biasP;
    const float* xg;
    _Float16* h[6];
    int* flags;              // [6][25]
};

#define FTAIL                                                                 \
    __builtin_amdgcn_sched_barrier(0);                                        \
    asm volatile("s_waitcnt lgkmcnt(0)");                                     \
    __builtin_amdgcn_sched_barrier(0);                                        \
    __builtin_amdgcn_s_barrier();                                             \
    __builtin_amdgcn_sched_barrier(0);

#define PICK(A4) ((hi & 2) ? ((hi & 1) ? A4[3] : A4[2]) : ((hi & 1) ? A4[1] : A4[0]))

__device__ __forceinline__ int poll_flag(int* f, int t, int seen) {
    if (seen > t) return seen;
    int s = __hip_atomic_load(f, __ATOMIC_ACQUIRE, __HIP_MEMORY_SCOPE_AGENT);
    int tries = 0;
    while (s <= t && tries < (1 << 20)) {
        __builtin_amdgcn_s_sleep(8);
        s = __hip_atomic_load(f, __ATOMIC_ACQUIRE, __HIP_MEMORY_SCOPE_AGENT);
        ++tries;
    }
    return (s <= t) ? 1000 : s;  // bound tripped: give up (no hang)
}

// ----- layer 0 body: round-7 proven structure + flag publication -----------
__device__ void body0(const FusedPtrs& p, int bg, _Float16 (&hb)[2][4][144]) {
    constexpr int H = 128;
    constexpr int XSTR = 448 * H;
    constexpr int HSTR = 112 * H;
    const int tid = threadIdx.x;
    const int w = tid >> 6, l = tid & 63, hi = l >> 4;
    const int col = w * 16 + (l & 15);

    half8 bw[4][4];
    #pragma unroll
    for (int G = 0; G < 4; ++G)
        #pragma unroll
        for (int kk = 0; kk < 4; ++kk)
            bw[G][kk] = *(const half8*)(p.whh[0] + (size_t)(G * H + col) * H + kk * 32 + hi * 8);

    const float* xp = p.xg + (size_t)bg * (4 * H * 4) + col * 16;
    _Float16* hop = p.h[0] + (size_t)(bg * 4 + hi) * H + col;
    int* flagOut = p.flags + bg;

    f32x4 P0[4], P1[4], P2[4];
#define XLOAD0(PA)                                                            \
    PA[0] = *(const f32x4*)(xp + 0);                                          \
    PA[1] = *(const f32x4*)(xp + 4);                                          \
    PA[2] = *(const f32x4*)(xp + 8);                                          \
    PA[3] = *(const f32x4*)(xp + 12);                                         \
    xp += XSTR;

    XLOAD0(P0)
    XLOAD0(P1)
    XLOAD0(P2)

    float cst = 0.f;

#define STEP0(PA, CUR, T)                                                     \
    {                                                                         \
        half8 afr[4];                                                         \
        _Pragma("unroll") for (int kk = 0; kk < 4; ++kk)                      \
            afr[kk] = *(const half8*)&hb[CUR][(l & 15) & 3][kk * 32 + hi * 8]; \
        f32x4 accI = PA[0], accF = PA[1], accG4 = PA[2], accO = PA[3];        \
        XLOAD0(PA)                                                            \
        _Pragma("unroll") for (int kk = 0; kk < 4; ++kk) {                    \
            accI = __builtin_amdgcn_mfma_f32_16x16x32_f16(afr[kk], bw[0][kk], accI, 0, 0, 0);  \
            accF = __builtin_amdgcn_mfma_f32_16x16x32_f16(afr[kk], bw[1][kk], accF, 0, 0, 0);  \
            accG4 = __builtin_amdgcn_mfma_f32_16x16x32_f16(afr[kk], bw[2][kk], accG4, 0, 0, 0);\
            accO = __builtin_amdgcn_mfma_f32_16x16x32_f16(afr[kk], bw[3][kk], accO, 0, 0, 0);  \
        }                                                                     \
        float gI = PICK(accI), gF = PICK(accF), gG = PICK(accG4), gO = PICK(accO); \
        float si = sigmf(gI), sf = sigmf(gF), tg = tanhx(gG), so = sigmf(gO); \
        float cn = sf * cst + si * tg;                                        \
        cst = cn;                                                             \
        float hn = so * tanhx(cn);                                            \
        _Float16 hv = (_Float16)hn;                                           \
        hb[CUR ^ 1][hi][col] = hv;                                            \
        *hop = hv;                                                            \
        hop += HSTR;                                                          \
        const bool fs = (((T) & 1) == 1) | ((T) == 74);                       \
        if (fs) __builtin_amdgcn_fence(__ATOMIC_RELEASE, "agent");            \
        FTAIL                                                                 \
        if (fs & (tid == 0))                                                  \
            __hip_atomic_store(flagOut, (T) + 1, __ATOMIC_RELEASE, __HIP_MEMORY_SCOPE_AGENT); \
    }

    #pragma unroll 1
    for (int it = 0; it < 12; ++it) {
        const int b6 = it * 6;
        STEP0(P0, 0, b6 + 0) STEP0(P1, 1, b6 + 1) STEP0(P2, 0, b6 + 2)
        STEP0(P0, 1, b6 + 3) STEP0(P1, 0, b6 + 4) STEP0(P2, 1, b6 + 5)
    }
    STEP0(P0, 0, 72) STEP0(P1, 1, 73) STEP0(P2, 0, 74)
#undef STEP0
#undef XLOAD0
}

// ----- layers 1..5 body -----------------------------------------------------
template <int H, int HIN, int LYR>
__device__ void bodyN(const FusedPtrs& p, int bg, _Float16 (&hb)[2][4][144]) {
    constexpr int Ks = H / 32, KsI = HIN / 32;
    constexpr int nW = H / 16;
    constexpr int HSTR = 112 * H;
    constexpr int BOFF = (LYR == 1) ? 0 : (LYR == 2) ? 512 : (LYR == 3) ? 768
                         : (LYR == 4) ? 1024 : 1152;
    const int tid = threadIdx.x;
    const int w = tid >> 6, l = tid & 63, hi = l >> 4;

    int* flagIn = p.flags + (LYR - 1) * 25 + bg;
    int* flagOut = p.flags + LYR * 25 + bg;

    if (w < nW) {
        const int col = w * 16 + (l & 15);
        half8 bw[4][Ks], bw2[4][KsI];
        #pragma unroll
        for (int G = 0; G < 4; ++G) {
            #pragma unroll
            for (int kk = 0; kk < Ks; ++kk)
                bw[G][kk] = *(const half8*)(p.whh[LYR] + (size_t)(G * H + col) * H + kk * 32 + hi * 8);
            #pragma unroll
            for (int kk = 0; kk < KsI; ++kk)
                bw2[G][kk] = *(const half8*)(p.wih[LYR] + (size_t)(G * H + col) * HIN + kk * 32 + hi * 8);
        }
        const float* bp = p.biasP + BOFF;
        const float bI = bp[0 * H + col], bF = bp[1 * H + col];
        const float bG = bp[2 * H + col], bO = bp[3 * H + col];
        const _Float16* hin = p.h[LYR - 1] + (size_t)(bg * 4 + ((l & 15) & 3)) * HIN + hi * 8;
        _Float16* hop = p.h[LYR] + (size_t)(bg * 4 + hi) * H + col;
        float cst = 0.f;
        int seen = 0;

        #pragma unroll 1
        for (int t = 0; t < 75; ++t) {
            seen = poll_flag(flagIn, t, seen);
            half8 air[KsI];
            #pragma unroll
            for (int kk = 0; kk < KsI; ++kk)
                air[kk] = *(const half8*)(hin + (size_t)t * (112 * HIN) + kk * 32);
            const int cur = t & 1;
            half8 afr[Ks];
            #pragma unroll
            for (int kk = 0; kk < Ks; ++kk)
                afr[kk] = *(const half8*)&hb[cur][(l & 15) & 3][kk * 32 + hi * 8];
            f32x4 accI = {bI, bI, bI, bI}, accF = {bF, bF, bF, bF};
            f32x4 accG4 = {bG, bG, bG, bG}, accO = {bO, bO, bO, bO};
            #pragma unroll
            for (int kk = 0; kk < Ks; ++kk) {
                accI = __builtin_amdgcn_mfma_f32_16x16x32_f16(afr[kk], bw[0][kk], accI, 0, 0, 0);
                accF = __builtin_amdgcn_mfma_f32_16x16x32_f16(afr[kk], bw[1][kk], accF, 0, 0, 0);
                accG4 = __builtin_amdgcn_mfma_f32_16x16x32_f16(afr[kk], bw[2][kk], accG4, 0, 0, 0);
                accO = __builtin_amdgcn_mfma_f32_16x16x32_f16(afr[kk], bw[3][kk], accO, 0, 0, 0);
            }
            #pragma unroll
            for (int kk = 0; kk < KsI; ++kk) {
                accI = __builtin_amdgcn_mfma_f32_16x16x32_f16(air[kk], bw2[0][kk], accI, 0, 0, 0);
                accF = __builtin_amdgcn_mfma_f32_16x16x32_f16(air[kk], bw2[1][kk], accF, 0, 0, 0);
                accG4 = __builtin_amdgcn_mfma_f32_16x16x32_f16(air[kk], bw2[2][kk], accG4, 0, 0, 0);
                accO = __builtin_amdgcn_mfma_f32_16x16x32_f16(air[kk], bw2[3][kk], accO, 0, 0, 0);
            }
            float gI = PICK(accI), gF = PICK(accF), gG = PICK(accG4), gO = PICK(accO);
            float si = sigmf(gI), sf = sigmf(gF), tg = tanhx(gG), so = sigmf(gO);
            float cn = sf * cst + si * tg;
            cst = cn;
            float hn = so * tanhx(cn);
            _Float16 hv = (_Float16)hn;
            hb[cur ^ 1][hi][col] = hv;
            hop[(size_t)t * HSTR] = hv;
            const bool fs = ((t & 1) == 1) | (t == 74);
            if (fs) __builtin_amdgcn_fence(__ATOMIC_RELEASE, "agent");
            FTAIL
            if (LYR < 5) {
                if (fs & (tid == 0))
                    __hip_atomic_store(flagOut, t + 1, __ATOMIC_RELEASE, __HIP_MEMORY_SCOPE_AGENT);
            }
        }
    } else {
        #pragma unroll 1
        for (int t = 0; t < 75; ++t) { FTAIL }
    }
}

__global__ __launch_bounds__(512) void lstm_fused(FusedPtrs p) {
    __shared__ __align__(16) _Float16 hb[2][4][144];
    const int layer = blockIdx.x / 25;
    const int bg = blockIdx.x - layer * 25;
    for (int i = threadIdx.x; i < 2 * 4 * 144; i += 512) ((_Float16*)hb)[i] = (_Float16)0;
    __syncthreads();
    if (layer == 0) body0(p, bg, hb);
    else if (layer == 1) bodyN<128, 128, 1>(p, bg, hb);
    else if (layer == 2) bodyN<64, 128, 2>(p, bg, hb);
    else if (layer == 3) bodyN<64, 64, 3>(p, bg, hb);
    else if (layer == 4) bodyN<32, 64, 4>(p, bg, hb);
    else bodyN<32, 32, 5>(p, bg, hb);
}

// ---------------------------------------------------------------------------
// Final linear: out[100][60] = h5 @ lin_w^T + lin_b; h5 is [75][112][32] fp16.
// ---------------------------------------------------------------------------
__global__ __launch_bounds__(256) void linear_out(
    const _Float16* __restrict__ h, const float* __restrict__ lw,
    const float* __restrict__ lb, float* __restrict__ out) {
    int wave = (blockIdx.x * 256 + threadIdx.x) >> 6;
    int l = threadIdx.x & 63;
    if (wave >= 6000) return;
    int b = wave / 60, o = wave - b * 60;
    int hc = l & 31, t0 = l >> 5;
    float acc = 0.f;
    for (int t = t0; t < 75; t += 2)
        acc += (float)h[((size_t)t * 112 + b) * 32 + hc] * lw[(size_t)o * 2400 + t * 32 + hc];
    #pragma unroll
    for (int s = 32; s; s >>= 1) acc += __shfl_xor(acc, s, 64);
    if (l == 0) out[b * 60 + o] = acc + lb[o];
}

// ---------------------------------------------------------------------------
extern "C" void kernel_launch(void* const* d_in, const int* in_sizes, int n_in,
                              void* d_out, int out_size, void* d_ws, size_t ws_size,
                              hipStream_t stream) {
    const float* x = (const float*)d_in[0];
    const float* wih[6];
    const float* whhp[6];
    const float* bih[6];
    const float* bhh[6];
    for (int i = 0; i < 6; ++i) {
        wih[i] = (const float*)d_in[1 + 4 * i];
        whhp[i] = (const float*)d_in[2 + 4 * i];
        bih[i] = (const float*)d_in[3 + 4 * i];
        bhh[i] = (const float*)d_in[4 + 4 * i];
    }
    const float* lw = (const float*)d_in[25];
    const float* lb = (const float*)d_in[26];
    float* out = (float*)d_out;

    char* ws = (char*)d_ws;
    size_t cur = 0;
    auto alloc = [&](size_t b) {
        size_t o = cur;
        cur += (b + 255) & ~(size_t)255;
        return o;
    };
    _Float16* x16 = (_Float16*)(ws + alloc((size_t)8448 * 76 * 2));
    _Float16* wihI0 = (_Float16*)(ws + alloc(77824));
    _Float16* wihP[6];
    const size_t wihBytes[6] = {0, 131072, 65536, 32768, 16384, 8192};
    wihP[0] = nullptr;
    for (int i = 1; i < 6; ++i) wihP[i] = (_Float16*)(ws + alloc(wihBytes[i]));
    _Float16* whhP[6];
    const size_t whhBytes[6] = {131072, 131072, 32768, 32768, 8192, 8192};
    for (int i = 0; i < 6; ++i) whhP[i] = (_Float16*)(ws + alloc(whhBytes[i]));
    float* biasI0 = (float*)(ws + alloc(512 * 4));
    float* biasP = (float*)(ws + alloc(1280 * 4));
    float* xg = (float*)(ws + alloc((size_t)78 * 28 * 512 * 4 * 4));
    _Float16* hP[6];
    const int HH[6] = {128, 128, 64, 64, 32, 32};
    for (int i = 0; i < 6; ++i)
        hP[i] = (_Float16*)(ws + alloc((size_t)75 * 112 * HH[i] * 2));
    int* flags = (int*)(ws + alloc(6 * 25 * 4));

    hipMemsetAsync(flags, 0, 6 * 25 * 4, stream);

    PrepPtrs pp;
    for (int i = 0; i < 6; ++i) {
        pp.wih[i] = wih[i];
        pp.whh[i] = whhp[i];
        pp.bi[i] = bih[i];
        pp.bh[i] = bhh[i];
        pp.wihP[i] = (i == 0) ? wihP[1] : wihP[i];  // [0] never written
        pp.whhP[i] = whhP[i];
    }
    pp.x = x;
    pp.wihI0 = wihI0;
    pp.biasI0 = biasI0;
    pp.biasP = biasP;
    pp.x16 = x16;
    prep_kernel<<<3835, 256, 0, stream>>>(pp);

    gemm_xg<3><<<dim3(150, 8), 256, 0, stream>>>(x16, wihI0, biasI0, xg, 76, 512);

    FusedPtrs fp;
    for (int i = 0; i < 6; ++i) {
        fp.whh[i] = whhP[i];
        fp.wih[i] = (i == 0) ? whhP[0] : wihP[i];  // [0] never read
        fp.h[i] = hP[i];
    }
    fp.biasP = biasP;
    fp.xg = xg;
    fp.flags = flags;
    lstm_fused<<<150, 512, 0, stream>>>(fp);

    linear_out<<<1500, 256, 0, stream>>>(hP[5], lw, lb, out);
}

// Round 9
// 230.541 us; speedup vs baseline: 3.4071x; 3.4071x over previous
//
#include <hip/hip_runtime.h>

using half8 = __attribute__((ext_vector_type(8))) _Float16;
using f32x4 = __attribute__((ext_vector_type(4))) float;

__device__ __forceinline__ float sigmf(float x) {
    return __builtin_amdgcn_rcpf(1.0f + __expf(-x));
}
__device__ __forceinline__ float tanhx(float x) {
    return 1.0f - 2.0f * __builtin_amdgcn_rcpf(1.0f + __expf(x + x));
}

// ---------------------------------------------------------------------------
// Prep (one-time, parallel):
//  x16   : [75][112][76] fp16 (transposed x, zero-padded)
//  wihI{0,1,2,4}: GEMM-interleaved [4H][Kv] fp16 (row n = gate row
//                 (n&3)*H + (n>>2)) for the xg-GEMM layers 0,1,2,4
//  wihP{3,5}    : plain [4H][HIN] fp16 for the in-register pair-B layers
//  whhP  : all layers plain [4H][H] fp16
//  biasI : summed b_ih+b_hh, interleaved, layers 0,1,2,4 (gemm bias)
//  biasP : summed b_ih+b_hh, plain, layers 3,5 (pair-B C-init)
// ---------------------------------------------------------------------------
struct PrepPtrs {
    const float* wih[6];
    const float* whh[6];
    const float* bi[6];
    const float* bh[6];
    const float* x;
    _Float16* wihI0;
    _Float16* wihI1;
    _Float16* wihI2;
    _Float16* wihI4;
    _Float16* wihP3;
    _Float16* wihP5;
    _Float16* whhP[6];
    float* biasI;  // L0@0, L1@512, L2@1024, L4@1280
    float* biasP;  // L3@0, L5@256
    _Float16* x16;
};

__global__ __launch_bounds__(256) void prep_kernel(PrepPtrs p) {
    int i = blockIdx.x * 256 + threadIdx.x;
    if (i < 642048) {  // x16: 8448 rows x 76
        int row = i / 76, k = i - row * 76;
        int t = row / 112, b = row - t * 112;
        float v = (b < 100 && k < 75 && t < 75)
                      ? p.x[((size_t)b * 75 + t) * 75 + k]
                      : 0.0f;
        p.x16[i] = (_Float16)v;
        return;
    }
    i -= 642048;
    if (i < 38912) {  // wihI0 [512][76], K=75
        int n = i / 76, k = i - n * 76;
        int col = n >> 2, G = n & 3;
        float v = (k < 75) ? p.wih[0][(size_t)(G * 128 + col) * 75 + k] : 0.0f;
        p.wihI0[i] = (_Float16)v;
        return;
    }
    i -= 38912;
    if (i < 65536) {  // wihI1 [512][128]
        int n = i >> 7, k = i & 127;
        int col = n >> 2, G = n & 3;
        p.wihI1[i] = (_Float16)p.wih[1][(size_t)(G * 128 + col) * 128 + k];
        return;
    }
    i -= 65536;
    if (i < 32768) {  // wihI2 [256][128]
        int n = i >> 7, k = i & 127;
        int col = n >> 2, G = n & 3;
        p.wihI2[i] = (_Float16)p.wih[2][(size_t)(G * 64 + col) * 128 + k];
        return;
    }
    i -= 32768;
    if (i < 8192) {  // wihI4 [128][64]
        int n = i >> 6, k = i & 63;
        int col = n >> 2, G = n & 3;
        p.wihI4[i] = (_Float16)p.wih[4][(size_t)(G * 32 + col) * 64 + k];
        return;
    }
    i -= 8192;
    if (i < 16384) { p.wihP3[i] = (_Float16)p.wih[3][i]; return; }
    i -= 16384;
    if (i < 4096) { p.wihP5[i] = (_Float16)p.wih[5][i]; return; }
    i -= 4096;
    constexpr int WHHC[6] = {65536, 65536, 16384, 16384, 4096, 4096};
    #pragma unroll
    for (int l = 0; l < 6; ++l) {
        if (i < WHHC[l]) { p.whhP[l][i] = (_Float16)p.whh[l][i]; return; }
        i -= WHHC[l];
    }
    // biasI interleaved: L0,L1 (H=128), L2 (64), L4 (32)
    constexpr int BIL[4] = {0, 1, 2, 4};
    constexpr int BIH[4] = {128, 128, 64, 32};
    constexpr int BIO[4] = {0, 512, 1024, 1280};
    #pragma unroll
    for (int j = 0; j < 4; ++j) {
        int cnt = 4 * BIH[j];
        if (i < cnt) {
            int col = i >> 2, G = i & 3;
            int src = G * BIH[j] + col;
            int l = BIL[j];
            p.biasI[BIO[j] + i] = p.bi[l][src] + p.bh[l][src];
            return;
        }
        i -= cnt;
    }
    if (i < 256) { p.biasP[i] = p.bi[3][i] + p.bh[3][i]; return; }
    i -= 256;
    if (i < 128) { p.biasP[256 + i] = p.bi[5][i] + p.bh[5][i]; return; }
}

// ---------------------------------------------------------------------------
// xg GEMM (round-7 proven): xg[t][bx][n][bs], layout [75][28][4H][4] f32;
// a lane's f32x4 at (n, bs0..3) is one MFMA C fragment (rows = batch).
// ---------------------------------------------------------------------------
template <int Ks>
__global__ __launch_bounds__(256) void gemm_xg(
    const _Float16* __restrict__ A, const _Float16* __restrict__ W,
    const float* __restrict__ bias, float* __restrict__ C, int Kv, int N) {
    constexpr int KP = Ks * 32;
    constexpr int LDK = KP + 8;
    __shared__ __align__(16) _Float16 Al[64][LDK];
    __shared__ __align__(16) _Float16 Wl[64][LDK];

    const int tid = threadIdx.x;
    const int tt = blockIdx.x >> 1;
    const int boff = (blockIdx.x & 1) * 48;
    const int n0 = blockIdx.y * 64;
    constexpr int HP = KP / 2;

    for (int idx = tid; idx < 64 * HP; idx += 256) {
        int row = idx / HP;
        int k = (idx - row * HP) * 2;
        unsigned int va = 0, vw = 0;
        if (k < Kv) {
            va = *(const unsigned int*)(A + (size_t)(tt * 112 + boff + row) * Kv + k);
            vw = *(const unsigned int*)(W + (size_t)(n0 + row) * Kv + k);
        }
        *(unsigned int*)&Al[row][k] = va;
        *(unsigned int*)&Wl[row][k] = vw;
    }
    __syncthreads();

    const int w = tid >> 6, l = tid & 63, hi = l >> 4;
    half8 a[Ks];
    #pragma unroll
    for (int kk = 0; kk < Ks; ++kk)
        a[kk] = *(const half8*)&Al[w * 16 + (l & 15)][kk * 32 + hi * 8];

    f32x4 acc[4];
    #pragma unroll
    for (int jt = 0; jt < 4; ++jt) {
        acc[jt] = f32x4{0.f, 0.f, 0.f, 0.f};
        #pragma unroll
        for (int kk = 0; kk < Ks; ++kk) {
            half8 b = *(const half8*)&Wl[jt * 16 + (l & 15)][kk * 32 + hi * 8];
            acc[jt] = __builtin_amdgcn_mfma_f32_16x16x32_f16(a[kk], b, acc[jt], 0, 0, 0);
        }
    }

    const int bx = (boff >> 2) + w * 4 + hi;
    #pragma unroll
    for (int jt = 0; jt < 4; ++jt) {
        int n = n0 + jt * 16 + (l & 15);
        float bs = bias[n];
        f32x4 v = acc[jt];
        v[0] += bs; v[1] += bs; v[2] += bs; v[3] += bs;
        *(f32x4*)(C + ((size_t)(tt * 28 + bx) * N + n) * 4) = v;
    }
}

#define FTAIL                                                                 \
    __builtin_amdgcn_sched_barrier(0);                                        \
    asm volatile("s_waitcnt lgkmcnt(0)");                                     \
    __builtin_amdgcn_sched_barrier(0);                                        \
    __builtin_amdgcn_s_barrier();                                             \
    __builtin_amdgcn_sched_barrier(0);

#define PICK(A4) ((hi & 2) ? ((hi & 1) ? A4[3] : A4[2]) : ((hi & 1) ? A4[1] : A4[0]))

// ---------------------------------------------------------------------------
// Single recurrent layer (round-7 proven, unchanged): 25 blocks x 4 batch
// rows, M-replication, one barrier per step, xg as MFMA C-init 3 steps deep.
// ---------------------------------------------------------------------------
template <int H>
__global__ __launch_bounds__(4 * H) void lstm_rec(
    const float* __restrict__ xg,       // [75+3][28][4H][4] f32
    const _Float16* __restrict__ whh,   // [4H][H] fp16
    _Float16* __restrict__ hout) {      // [75][112][H] fp16
    constexpr int Ks = H / 32;
    constexpr int LDH = H + 8;
    constexpr int XSTR = 448 * H;
    constexpr int HSTR = 112 * H;

    __shared__ __align__(16) _Float16 hbuf[2][4][LDH];

    const int tid = threadIdx.x;
    const int w = tid >> 6, l = tid & 63, hi = l >> 4;
    const int col = w * 16 + (l & 15);
    const int blk = blockIdx.x;

    half8 bw[4][Ks];
    #pragma unroll
    for (int G = 0; G < 4; ++G)
        #pragma unroll
        for (int kk = 0; kk < Ks; ++kk)
            bw[G][kk] = *(const half8*)(whh + (size_t)(G * H + col) * H + kk * 32 + hi * 8);

    for (int i = tid; i < 2 * 4 * LDH; i += 4 * H) ((_Float16*)hbuf)[i] = (_Float16)0;
    __syncthreads();

    const float* xp = xg + (size_t)blk * (4 * H * 4) + col * 16;
    _Float16* hop = hout + (size_t)(blk * 4 + hi) * H + col;

    f32x4 P0[4], P1[4], P2[4];
#define XLOAD(PA)                                                             \
    PA[0] = *(const f32x4*)(xp + 0);                                          \
    PA[1] = *(const f32x4*)(xp + 4);                                          \
    PA[2] = *(const f32x4*)(xp + 8);                                          \
    PA[3] = *(const f32x4*)(xp + 12);                                         \
    xp += XSTR;

    XLOAD(P0)
    XLOAD(P1)
    XLOAD(P2)

    float cst = 0.f;

#define LSTM_STEP(PA, CUR)                                                    \
    {                                                                         \
        half8 afr[Ks];                                                        \
        _Pragma("unroll") for (int kk = 0; kk < Ks; ++kk)                     \
            afr[kk] = *(const half8*)&hbuf[CUR][(l & 15) & 3][kk * 32 + hi * 8]; \
        f32x4 accI = PA[0], accF = PA[1], accG4 = PA[2], accO = PA[3];        \
        XLOAD(PA)                                                             \
        _Pragma("unroll") for (int kk = 0; kk < Ks; ++kk) {                   \
            accI = __builtin_amdgcn_mfma_f32_16x16x32_f16(afr[kk], bw[0][kk], accI, 0, 0, 0);  \
            accF = __builtin_amdgcn_mfma_f32_16x16x32_f16(afr[kk], bw[1][kk], accF, 0, 0, 0);  \
            accG4 = __builtin_amdgcn_mfma_f32_16x16x32_f16(afr[kk], bw[2][kk], accG4, 0, 0, 0);\
            accO = __builtin_amdgcn_mfma_f32_16x16x32_f16(afr[kk], bw[3][kk], accO, 0, 0, 0);  \
        }                                                                     \
        float gI = PICK(accI), gF = PICK(accF), gG = PICK(accG4), gO = PICK(accO); \
        float si = sigmf(gI), sf = sigmf(gF), tg = tanhx(gG), so = sigmf(gO); \
        float cn = sf * cst + si * tg;                                        \
        cst = cn;                                                             \
        float hn = so * tanhx(cn);                                            \
        _Float16 hv = (_Float16)hn;                                           \
        hbuf[CUR ^ 1][hi][col] = hv;                                          \
        *hop = hv;                                                            \
        hop += HSTR;                                                          \
        FTAIL                                                                 \
    }

    #pragma unroll 1
    for (int it = 0; it < 12; ++it) {
        LSTM_STEP(P0, 0) LSTM_STEP(P1, 1) LSTM_STEP(P2, 0)
        LSTM_STEP(P0, 1) LSTM_STEP(P1, 0) LSTM_STEP(P2, 1)
    }
    LSTM_STEP(P0, 0) LSTM_STEP(P1, 1) LSTM_STEP(P2, 0)
#undef LSTM_STEP
#undef XLOAD
}

// ---------------------------------------------------------------------------
// Fused layer PAIR (A, B), HA == HB == H, staggered by one step inside one
// block. Waves [0,NW) = layer A (identical to lstm_rec: xg C-init, 3-deep P);
// waves [NW,2NW) = layer B one step behind, consuming h^A from the LDS pipe
// hp[2][4][.] (written by A pre-barrier) -- no fences, no flags, one barrier
// per step, 76 steps for two layers. B computes whh*h^B + wih*h^A + bias with
// both weight sets in registers. Only B's h goes to global.
// ---------------------------------------------------------------------------
template <int H>
__global__ __launch_bounds__(8 * H) void lstm_pair(
    const float* __restrict__ xg,        // [75+3][28][4H][4] f32 (layer A)
    const _Float16* __restrict__ whhA,   // [4H][H]
    const _Float16* __restrict__ whhB,   // [4H][H]
    const _Float16* __restrict__ wihB,   // [4H][H]
    const float* __restrict__ biasB,     // [4H] plain (i,f,g,o blocks)
    _Float16* __restrict__ houtB) {      // [75][112][H]
    constexpr int Ks = H / 32;
    constexpr int NW = H / 16;
    constexpr int LDH = H + 8;
    constexpr int XSTR = 448 * H;
    constexpr int HSTR = 112 * H;

    __shared__ __align__(16) _Float16 hbA[2][4][LDH];
    __shared__ __align__(16) _Float16 hbB[2][4][LDH];
    __shared__ __align__(16) _Float16 hp[2][4][LDH];

    const int tid = threadIdx.x;
    const int w = tid >> 6, l = tid & 63, hi = l >> 4;
    const bool isA = (w < NW);
    const int wl = isA ? w : (w - NW);
    const int col = wl * 16 + (l & 15);
    const int blk = blockIdx.x;

    half8 bwA[4][Ks], bwB[4][Ks], bwI[4][Ks];
    float bI = 0.f, bF = 0.f, bG = 0.f, bO = 0.f;
    if (isA) {
        #pragma unroll
        for (int G = 0; G < 4; ++G)
            #pragma unroll
            for (int kk = 0; kk < Ks; ++kk)
                bwA[G][kk] = *(const half8*)(whhA + (size_t)(G * H + col) * H + kk * 32 + hi * 8);
    } else {
        #pragma unroll
        for (int G = 0; G < 4; ++G)
            #pragma unroll
            for (int kk = 0; kk < Ks; ++kk) {
                bwB[G][kk] = *(const half8*)(whhB + (size_t)(G * H + col) * H + kk * 32 + hi * 8);
                bwI[G][kk] = *(const half8*)(wihB + (size_t)(G * H + col) * H + kk * 32 + hi * 8);
            }
        bI = biasB[0 * H + col];
        bF = biasB[1 * H + col];
        bG = biasB[2 * H + col];
        bO = biasB[3 * H + col];
    }

    for (int i = tid; i < 2 * 4 * LDH; i += 8 * H) {
        ((_Float16*)hbA)[i] = (_Float16)0;
        ((_Float16*)hbB)[i] = (_Float16)0;
        ((_Float16*)hp)[i] = (_Float16)0;
    }
    __syncthreads();

    const float* xp = xg + (size_t)blk * (4 * H * 4) + col * 16;
    _Float16* hop = houtB + (size_t)(blk * 4 + hi) * H + col;

    f32x4 P0[4], P1[4], P2[4];
#define XLOADP(PA)                                                            \
    PA[0] = *(const f32x4*)(xp + 0);                                          \
    PA[1] = *(const f32x4*)(xp + 4);                                          \
    PA[2] = *(const f32x4*)(xp + 8);                                          \
    PA[3] = *(const f32x4*)(xp + 12);                                         \
    xp += XSTR;

    if (isA) {
        XLOADP(P0)
        XLOADP(P1)
        XLOADP(P2)
    }

    float cst = 0.f;  // lane is exclusively A or B -> one c-state each

#define ASTEP(PA, CUR)                                                        \
    {                                                                         \
        half8 afr[Ks];                                                        \
        _Pragma("unroll") for (int kk = 0; kk < Ks; ++kk)                     \
            afr[kk] = *(const half8*)&hbA[CUR][(l & 15) & 3][kk * 32 + hi * 8]; \
        f32x4 aI = PA[0], aF = PA[1], aG = PA[2], aO = PA[3];                 \
        XLOADP(PA)                                                            \
        _Pragma("unroll") for (int kk = 0; kk < Ks; ++kk) {                   \
            aI = __builtin_amdgcn_mfma_f32_16x16x32_f16(afr[kk], bwA[0][kk], aI, 0, 0, 0); \
            aF = __builtin_amdgcn_mfma_f32_16x16x32_f16(afr[kk], bwA[1][kk], aF, 0, 0, 0); \
            aG = __builtin_amdgcn_mfma_f32_16x16x32_f16(afr[kk], bwA[2][kk], aG, 0, 0, 0); \
            aO = __builtin_amdgcn_mfma_f32_16x16x32_f16(afr[kk], bwA[3][kk], aO, 0, 0, 0); \
        }                                                                     \
        float gI = PICK(aI), gF = PICK(aF), gG = PICK(aG), gO = PICK(aO);     \
        float si = sigmf(gI), sf = sigmf(gF), tg = tanhx(gG), so = sigmf(gO); \
        float cn = sf * cst + si * tg;                                        \
        cst = cn;                                                             \
        float hn = so * tanhx(cn);                                            \
        _Float16 hv = (_Float16)hn;                                           \
        hbA[CUR ^ 1][hi][col] = hv;                                           \
        hp[CUR ^ 1][hi][col] = hv;                                            \
    }

#define BSTEP(CUR)                                                            \
    {                                                                         \
        half8 afr[Ks], air[Ks];                                               \
        _Pragma("unroll") for (int kk = 0; kk < Ks; ++kk) {                   \
            afr[kk] = *(const half8*)&hbB[CUR][(l & 15) & 3][kk * 32 + hi * 8]; \
            air[kk] = *(const half8*)&hp[CUR][(l & 15) & 3][kk * 32 + hi * 8]; \
        }                                                                     \
        f32x4 aI = {bI, bI, bI, bI}, aF = {bF, bF, bF, bF};                   \
        f32x4 aG = {bG, bG, bG, bG}, aO = {bO, bO, bO, bO};                   \
        _Pragma("unroll") for (int kk = 0; kk < Ks; ++kk) {                   \
            aI = __builtin_amdgcn_mfma_f32_16x16x32_f16(afr[kk], bwB[0][kk], aI, 0, 0, 0); \
            aF = __builtin_amdgcn_mfma_f32_16x16x32_f16(afr[kk], bwB[1][kk], aF, 0, 0, 0); \
            aG = __builtin_amdgcn_mfma_f32_16x16x32_f16(afr[kk], bwB[2][kk], aG, 0, 0, 0); \
            aO = __builtin_amdgcn_mfma_f32_16x16x32_f16(afr[kk], bwB[3][kk], aO, 0, 0, 0); \
        }                                                                     \
        _Pragma("unroll") for (int kk = 0; kk < Ks; ++kk) {                   \
            aI = __builtin_amdgcn_mfma_f32_16x16x32_f16(air[kk], bwI[0][kk], aI, 0, 0, 0); \
            aF = __builtin_amdgcn_mfma_f32_16x16x32_f16(air[kk], bwI[1][kk], aF, 0, 0, 0); \
            aG = __builtin_amdgcn_mfma_f32_16x16x32_f16(air[kk], bwI[2][kk], aG, 0, 0, 0); \
            aO = __builtin_amdgcn_mfma_f32_16x16x32_f16(air[kk], bwI[3][kk], aO, 0, 0, 0); \
        }                                                                     \
        float gI = PICK(aI), gF = PICK(aF), gG = PICK(aG), gO = PICK(aO);     \
        float si = sigmf(gI), sf = sigmf(gF), tg = tanhx(gG), so = sigmf(gO); \
        float cn = sf * cst + si * tg;                                        \
        cst = cn;                                                             \
        float hn = so * tanhx(cn);                                            \
        _Float16 hv = (_Float16)hn;                                           \
        hbB[CUR ^ 1][hi][col] = hv;                                           \
        *hop = hv;                                                            \
        hop += HSTR;                                                          \
    }

#define PSTEP(PA, CUR, S)                                                     \
    {                                                                         \
        if (isA) {                                                            \
            ASTEP(PA, CUR)                                                    \
        } else if ((S) > 0) {                                                 \
            BSTEP(CUR)                                                        \
        }                                                                     \
        FTAIL                                                                 \
    }

    #pragma unroll 1
    for (int it = 0; it < 12; ++it) {
        const int b6 = it * 6;
        PSTEP(P0, 0, b6 + 0) PSTEP(P1, 1, b6 + 1) PSTEP(P2, 0, b6 + 2)
        PSTEP(P0, 1, b6 + 3) PSTEP(P1, 0, b6 + 4) PSTEP(P2, 1, b6 + 5)
    }
    PSTEP(P0, 0, 72) PSTEP(P1, 1, 73) PSTEP(P2, 0, 74)
    {  // s = 75: B finishes t = 74
        if (!isA) { BSTEP(1) }
        FTAIL
    }
#undef PSTEP
#undef BSTEP
#undef ASTEP
#undef XLOADP
}

// ---------------------------------------------------------------------------
// Final linear: out[100][60] = h5 @ lin_w^T + lin_b; h5 is [75][112][32] fp16.
// ---------------------------------------------------------------------------
__global__ __launch_bounds__(256) void linear_out(
    const _Float16* __restrict__ h, const float* __restrict__ lw,
    const float* __restrict__ lb, float* __restrict__ out) {
    int wave = (blockIdx.x * 256 + threadIdx.x) >> 6;
    int l = threadIdx.x & 63;
    if (wave >= 6000) return;
    int b = wave / 60, o = wave - b * 60;
    int hc = l & 31, t0 = l >> 5;
    float acc = 0.f;
    for (int t = t0; t < 75; t += 2)
        acc += (float)h[((size_t)t * 112 + b) * 32 + hc] * lw[(size_t)o * 2400 + t * 32 + hc];
    #pragma unroll
    for (int s = 32; s; s >>= 1) acc += __shfl_xor(acc, s, 64);
    if (l == 0) out[b * 60 + o] = acc + lb[o];
}

// ---------------------------------------------------------------------------
extern "C" void kernel_launch(void* const* d_in, const int* in_sizes, int n_in,
                              void* d_out, int out_size, void* d_ws, size_t ws_size,
                              hipStream_t stream) {
    const float* x = (const float*)d_in[0];
    const float* wih[6];
    const float* whhp[6];
    const float* bih[6];
    const float* bhh[6];
    for (int i = 0; i < 6; ++i) {
        wih[i] = (const float*)d_in[1 + 4 * i];
        whhp[i] = (const float*)d_in[2 + 4 * i];
        bih[i] = (const float*)d_in[3 + 4 * i];
        bhh[i] = (const float*)d_in[4 + 4 * i];
    }
    const float* lw = (const float*)d_in[25];
    const float* lb = (const float*)d_in[26];
    float* out = (float*)d_out;

    char* ws = (char*)d_ws;
    size_t cur = 0;
    auto alloc = [&](size_t b) {
        size_t o = cur;
        cur += (b + 255) & ~(size_t)255;
        return o;
    };
    _Float16* x16 = (_Float16*)(ws + alloc((size_t)8448 * 76 * 2));
    _Float16* wihI0 = (_Float16*)(ws + alloc(38912 * 2));
    _Float16* wihI1 = (_Float16*)(ws + alloc(65536 * 2));
    _Float16* wihI2 = (_Float16*)(ws + alloc(32768 * 2));
    _Float16* wihI4 = (_Float16*)(ws + alloc(8192 * 2));
    _Float16* wihP3 = (_Float16*)(ws + alloc(16384 * 2));
    _Float16* wihP5 = (_Float16*)(ws + alloc(4096 * 2));
    _Float16* whhP[6];
    const size_t whhBytes[6] = {131072, 131072, 32768, 32768, 8192, 8192};
    for (int i = 0; i < 6; ++i) whhP[i] = (_Float16*)(ws + alloc(whhBytes[i]));
    float* biasI = (float*)(ws + alloc(1408 * 4));
    float* biasP = (float*)(ws + alloc(384 * 4));
    float* xg = (float*)(ws + alloc((size_t)78 * 28 * 512 * 4 * 4));  // +3t slack
    _Float16* h0 = (_Float16*)(ws + alloc((size_t)75 * 112 * 128 * 2));
    _Float16* h1 = (_Float16*)(ws + alloc((size_t)75 * 112 * 128 * 2));
    _Float16* h3 = (_Float16*)(ws + alloc((size_t)75 * 112 * 64 * 2));
    _Float16* h5 = (_Float16*)(ws + alloc((size_t)75 * 112 * 32 * 2));

    PrepPtrs pp;
    for (int i = 0; i < 6; ++i) {
        pp.wih[i] = wih[i];
        pp.whh[i] = whhp[i];
        pp.bi[i] = bih[i];
        pp.bh[i] = bhh[i];
        pp.whhP[i] = whhP[i];
    }
    pp.x = x;
    pp.wihI0 = wihI0;
    pp.wihI1 = wihI1;
    pp.wihI2 = wihI2;
    pp.wihI4 = wihI4;
    pp.wihP3 = wihP3;
    pp.wihP5 = wihP5;
    pp.biasI = biasI;
    pp.biasP = biasP;
    pp.x16 = x16;
    prep_kernel<<<3835, 256, 0, stream>>>(pp);

    // layer 0: I=75 (Kv=76), H=128
    gemm_xg<3><<<dim3(150, 8), 256, 0, stream>>>(x16, wihI0, biasI + 0, xg, 76, 512);
    lstm_rec<128><<<25, 512, 0, stream>>>(xg, whhP[0], h0);
    // layer 1: I=128, H=128
    gemm_xg<4><<<dim3(150, 8), 256, 0, stream>>>(h0, wihI1, biasI + 512, xg, 128, 512);
    lstm_rec<128><<<25, 512, 0, stream>>>(xg, whhP[1], h1);
    // layers 2+3 fused: layer2 via xg GEMM (I=128, H=64), layer3 in-register
    gemm_xg<4><<<dim3(150, 4), 256, 0, stream>>>(h1, wihI2, biasI + 1024, xg, 128, 256);
    lstm_pair<64><<<25, 512, 0, stream>>>(xg, whhP[2], whhP[3], wihP3, biasP + 0, h3);
    // layers 4+5 fused: layer4 via xg GEMM (I=64, H=32), layer5 in-register
    gemm_xg<2><<<dim3(150, 2), 256, 0, stream>>>(h3, wihI4, biasI + 1280, xg, 64, 128);
    lstm_pair<32><<<25, 256, 0, stream>>>(xg, whhP[4], whhP[5], wihP5, biasP + 256, h5);

    linear_out<<<1500, 256, 0, stream>>>(h5, lw, lb, out);
}

// Round 10
// 187.109 us; speedup vs baseline: 4.1980x; 1.2321x over previous
//
#include <hip/hip_runtime.h>

using half8 = __attribute__((ext_vector_type(8))) _Float16;
using f32x4 = __attribute__((ext_vector_type(4))) float;

__device__ __forceinline__ float sigmf(float x) {
    return __builtin_amdgcn_rcpf(1.0f + __expf(-x));
}
__device__ __forceinline__ float tanhx(float x) {
    return 1.0f - 2.0f * __builtin_amdgcn_rcpf(1.0f + __expf(x + x));
}

// ---------------------------------------------------------------------------
// Prep (one-time):
//  x16   : [75][112][76] fp16 (transposed x, zero-padded)
//  wihI{0,1,2}: GEMM-interleaved [4H][Kv] fp16 (row n = gate row
//               (n&3)*H + (n>>2)) for the xg-GEMM layers 0,1,2
//  wihP{3,4,5}: plain [4H][HIN] fp16 (in-register quad roles)
//  whhP  : all layers plain [4H][H] fp16
//  biasI : summed bias, interleaved, layers 0(@0),1(@512),2(@1024)
//  biasP : summed bias, plain, layers 3(@0),4(@256),5(@384)
// ---------------------------------------------------------------------------
struct PrepPtrs {
    const float* wih[6];
    const float* whh[6];
    const float* bi[6];
    const float* bh[6];
    const float* x;
    _Float16* wihI0;
    _Float16* wihI1;
    _Float16* wihI2;
    _Float16* wihP3;
    _Float16* wihP4;
    _Float16* wihP5;
    _Float16* whhP[6];
    float* biasI;
    float* biasP;
    _Float16* x16;
};

__global__ __launch_bounds__(256) void prep_kernel(PrepPtrs p) {
    int i = blockIdx.x * 256 + threadIdx.x;
    if (i < 642048) {  // x16: 8448 rows x 76
        int row = i / 76, k = i - row * 76;
        int t = row / 112, b = row - t * 112;
        float v = (b < 100 && k < 75 && t < 75)
                      ? p.x[((size_t)b * 75 + t) * 75 + k]
                      : 0.0f;
        p.x16[i] = (_Float16)v;
        return;
    }
    i -= 642048;
    if (i < 38912) {  // wihI0 [512][76], K=75
        int n = i / 76, k = i - n * 76;
        int col = n >> 2, G = n & 3;
        float v = (k < 75) ? p.wih[0][(size_t)(G * 128 + col) * 75 + k] : 0.0f;
        p.wihI0[i] = (_Float16)v;
        return;
    }
    i -= 38912;
    if (i < 65536) {  // wihI1 [512][128]
        int n = i >> 7, k = i & 127;
        int col = n >> 2, G = n & 3;
        p.wihI1[i] = (_Float16)p.wih[1][(size_t)(G * 128 + col) * 128 + k];
        return;
    }
    i -= 65536;
    if (i < 32768) {  // wihI2 [256][128]
        int n = i >> 7, k = i & 127;
        int col = n >> 2, G = n & 3;
        p.wihI2[i] = (_Float16)p.wih[2][(size_t)(G * 64 + col) * 128 + k];
        return;
    }
    i -= 32768;
    if (i < 16384) { p.wihP3[i] = (_Float16)p.wih[3][i]; return; }
    i -= 16384;
    if (i < 8192) { p.wihP4[i] = (_Float16)p.wih[4][i]; return; }
    i -= 8192;
    if (i < 4096) { p.wihP5[i] = (_Float16)p.wih[5][i]; return; }
    i -= 4096;
    constexpr int WHHC[6] = {65536, 65536, 16384, 16384, 4096, 4096};
    #pragma unroll
    for (int l = 0; l < 6; ++l) {
        if (i < WHHC[l]) { p.whhP[l][i] = (_Float16)p.whh[l][i]; return; }
        i -= WHHC[l];
    }
    // biasI interleaved: L0(H=128)@0, L1(128)@512, L2(64)@1024
    constexpr int BIH[3] = {128, 128, 64};
    constexpr int BIO[3] = {0, 512, 1024};
    #pragma unroll
    for (int j = 0; j < 3; ++j) {
        int cnt = 4 * BIH[j];
        if (i < cnt) {
            int col = i >> 2, G = i & 3;
            int src = G * BIH[j] + col;
            p.biasI[BIO[j] + i] = p.bi[j][src] + p.bh[j][src];
            return;
        }
        i -= cnt;
    }
    if (i < 256) { p.biasP[i] = p.bi[3][i] + p.bh[3][i]; return; }
    i -= 256;
    if (i < 128) { p.biasP[256 + i] = p.bi[4][i] + p.bh[4][i]; return; }
    i -= 128;
    if (i < 128) { p.biasP[384 + i] = p.bi[5][i] + p.bh[5][i]; return; }
}

// ---------------------------------------------------------------------------
// xg GEMM (round-7 proven): layout [75][28][4H][4] f32; a lane's f32x4 at
// (n, bs0..3) is one MFMA C fragment (rows = batch).
// ---------------------------------------------------------------------------
template <int Ks>
__global__ __launch_bounds__(256) void gemm_xg(
    const _Float16* __restrict__ A, const _Float16* __restrict__ W,
    const float* __restrict__ bias, float* __restrict__ C, int Kv, int N) {
    constexpr int KP = Ks * 32;
    constexpr int LDK = KP + 8;
    __shared__ __align__(16) _Float16 Al[64][LDK];
    __shared__ __align__(16) _Float16 Wl[64][LDK];

    const int tid = threadIdx.x;
    const int tt = blockIdx.x >> 1;
    const int boff = (blockIdx.x & 1) * 48;
    const int n0 = blockIdx.y * 64;
    constexpr int HP = KP / 2;

    for (int idx = tid; idx < 64 * HP; idx += 256) {
        int row = idx / HP;
        int k = (idx - row * HP) * 2;
        unsigned int va = 0, vw = 0;
        if (k < Kv) {
            va = *(const unsigned int*)(A + (size_t)(tt * 112 + boff + row) * Kv + k);
            vw = *(const unsigned int*)(W + (size_t)(n0 + row) * Kv + k);
        }
        *(unsigned int*)&Al[row][k] = va;
        *(unsigned int*)&Wl[row][k] = vw;
    }
    __syncthreads();

    const int w = tid >> 6, l = tid & 63, hi = l >> 4;
    half8 a[Ks];
    #pragma unroll
    for (int kk = 0; kk < Ks; ++kk)
        a[kk] = *(const half8*)&Al[w * 16 + (l & 15)][kk * 32 + hi * 8];

    f32x4 acc[4];
    #pragma unroll
    for (int jt = 0; jt < 4; ++jt) {
        acc[jt] = f32x4{0.f, 0.f, 0.f, 0.f};
        #pragma unroll
        for (int kk = 0; kk < Ks; ++kk) {
            half8 b = *(const half8*)&Wl[jt * 16 + (l & 15)][kk * 32 + hi * 8];
            acc[jt] = __builtin_amdgcn_mfma_f32_16x16x32_f16(a[kk], b, acc[jt], 0, 0, 0);
        }
    }

    const int bx = (boff >> 2) + w * 4 + hi;
    #pragma unroll
    for (int jt = 0; jt < 4; ++jt) {
        int n = n0 + jt * 16 + (l & 15);
        float bs = bias[n];
        f32x4 v = acc[jt];
        v[0] += bs; v[1] += bs; v[2] += bs; v[3] += bs;
        *(f32x4*)(C + ((size_t)(tt * 28 + bx) * N + n) * 4) = v;
    }
}

#define FTAIL                                                                 \
    __builtin_amdgcn_sched_barrier(0);                                        \
    asm volatile("s_waitcnt lgkmcnt(0)");                                     \
    __builtin_amdgcn_sched_barrier(0);                                        \
    __builtin_amdgcn_s_barrier();                                             \
    __builtin_amdgcn_sched_barrier(0);

#define PICK(A4) ((hi & 2) ? ((hi & 1) ? A4[3] : A4[2]) : ((hi & 1) ? A4[1] : A4[0]))

#define ACT(aI, aF, aG4, aO)                                                  \
    float gI = PICK(aI), gF = PICK(aF), gG = PICK(aG4), gO = PICK(aO);        \
    float si = sigmf(gI), sf = sigmf(gF), tg = tanhx(gG), so = sigmf(gO);     \
    float cn = sf * cst + si * tg;                                            \
    cst = cn;                                                                 \
    float hn = so * tanhx(cn);                                                \
    _Float16 hv = (_Float16)hn;

// ---------------------------------------------------------------------------
// Single recurrent layer (round-7 proven, unchanged).
// ---------------------------------------------------------------------------
template <int H>
__global__ __launch_bounds__(4 * H) void lstm_rec(
    const float* __restrict__ xg, const _Float16* __restrict__ whh,
    _Float16* __restrict__ hout) {
    constexpr int Ks = H / 32;
    constexpr int LDH = H + 8;
    constexpr int XSTR = 448 * H;
    constexpr int HSTR = 112 * H;

    __shared__ __align__(16) _Float16 hbuf[2][4][LDH];

    const int tid = threadIdx.x;
    const int w = tid >> 6, l = tid & 63, hi = l >> 4;
    const int col = w * 16 + (l & 15);
    const int blk = blockIdx.x;

    half8 bw[4][Ks];
    #pragma unroll
    for (int G = 0; G < 4; ++G)
        #pragma unroll
        for (int kk = 0; kk < Ks; ++kk)
            bw[G][kk] = *(const half8*)(whh + (size_t)(G * H + col) * H + kk * 32 + hi * 8);

    for (int i = tid; i < 2 * 4 * LDH; i += 4 * H) ((_Float16*)hbuf)[i] = (_Float16)0;
    __syncthreads();

    const float* xp = xg + (size_t)blk * (4 * H * 4) + col * 16;
    _Float16* hop = hout + (size_t)(blk * 4 + hi) * H + col;

    f32x4 P0[4], P1[4], P2[4];
#define XLOAD(PA)                                                             \
    PA[0] = *(const f32x4*)(xp + 0);                                          \
    PA[1] = *(const f32x4*)(xp + 4);                                          \
    PA[2] = *(const f32x4*)(xp + 8);                                          \
    PA[3] = *(const f32x4*)(xp + 12);                                         \
    xp += XSTR;

    XLOAD(P0)
    XLOAD(P1)
    XLOAD(P2)

    float cst = 0.f;

#define LSTM_STEP(PA, CUR)                                                    \
    {                                                                         \
        half8 afr[Ks];                                                        \
        _Pragma("unroll") for (int kk = 0; kk < Ks; ++kk)                     \
            afr[kk] = *(const half8*)&hbuf[CUR][(l & 15) & 3][kk * 32 + hi * 8]; \
        f32x4 aI = PA[0], aF = PA[1], aG4 = PA[2], aO = PA[3];                \
        XLOAD(PA)                                                             \
        _Pragma("unroll") for (int kk = 0; kk < Ks; ++kk) {                   \
            aI = __builtin_amdgcn_mfma_f32_16x16x32_f16(afr[kk], bw[0][kk], aI, 0, 0, 0);  \
            aF = __builtin_amdgcn_mfma_f32_16x16x32_f16(afr[kk], bw[1][kk], aF, 0, 0, 0);  \
            aG4 = __builtin_amdgcn_mfma_f32_16x16x32_f16(afr[kk], bw[2][kk], aG4, 0, 0, 0);\
            aO = __builtin_amdgcn_mfma_f32_16x16x32_f16(afr[kk], bw[3][kk], aO, 0, 0, 0);  \
        }                                                                     \
        ACT(aI, aF, aG4, aO)                                                  \
        hbuf[CUR ^ 1][hi][col] = hv;                                          \
        *hop = hv;                                                            \
        hop += HSTR;                                                          \
        FTAIL                                                                 \
    }

    #pragma unroll 1
    for (int it = 0; it < 12; ++it) {
        LSTM_STEP(P0, 0) LSTM_STEP(P1, 1) LSTM_STEP(P2, 0)
        LSTM_STEP(P0, 1) LSTM_STEP(P1, 0) LSTM_STEP(P2, 1)
    }
    LSTM_STEP(P0, 0) LSTM_STEP(P1, 1) LSTM_STEP(P2, 0)
#undef LSTM_STEP
#undef XLOAD
}

// ---------------------------------------------------------------------------
// Quad-fused layers 2,3,4,5. 25 blocks x 768 threads (12 waves):
// w0-3 = L2 (H=64, xg C-init, round-7 A-role), w4-7 = L3 (H=64, lag 1),
// w8-9 = L4 (H=32, HIN=64, lag 2), w10-11 = L5 (H=32, lag 3, writes h5).
// Handoff via double-buffered LDS pipes. Parity rule: at global step s every
// role uses cur=s&1, reads own hb[cur] + upstream hp[cur], writes [cur^1]
// (producer publishes exactly one step before its consumer reads). 78 steps,
// one barrier each; all branches execute exactly 78 FTAILs.
// ---------------------------------------------------------------------------
__global__ __launch_bounds__(768) void lstm_quad(
    const float* __restrict__ xg,        // [78][28][256][4] f32 (layer 2)
    const _Float16* __restrict__ whh2, const _Float16* __restrict__ whh3,
    const _Float16* __restrict__ wih3, const _Float16* __restrict__ whh4,
    const _Float16* __restrict__ wih4, const _Float16* __restrict__ whh5,
    const _Float16* __restrict__ wih5, const float* __restrict__ biasP,
    _Float16* __restrict__ hout) {       // [75][112][32]
    __shared__ __align__(16) _Float16 hb2[2][4][72], hp2[2][4][72];
    __shared__ __align__(16) _Float16 hb3[2][4][72], hp3[2][4][72];
    __shared__ __align__(16) _Float16 hb4[2][4][40], hp4[2][4][40];
    __shared__ __align__(16) _Float16 hb5[2][4][40];

    const int tid = threadIdx.x;
    const int w = tid >> 6, l = tid & 63, hi = l >> 4;
    const int lr = (l & 15) & 3;
    const int blk = blockIdx.x;

    for (int i = tid; i < 2 * 4 * 72; i += 768) {
        ((_Float16*)hb2)[i] = (_Float16)0; ((_Float16*)hp2)[i] = (_Float16)0;
        ((_Float16*)hb3)[i] = (_Float16)0; ((_Float16*)hp3)[i] = (_Float16)0;
    }
    for (int i = tid; i < 2 * 4 * 40; i += 768) {
        ((_Float16*)hb4)[i] = (_Float16)0; ((_Float16*)hp4)[i] = (_Float16)0;
        ((_Float16*)hb5)[i] = (_Float16)0;
    }
    __syncthreads();

    float cst = 0.f;

    if (w < 4) {  // ----- L2: xg C-init role -----
        const int col = w * 16 + (l & 15);
        half8 bw[4][2];
        #pragma unroll
        for (int G = 0; G < 4; ++G)
            #pragma unroll
            for (int kk = 0; kk < 2; ++kk)
                bw[G][kk] = *(const half8*)(whh2 + (size_t)(G * 64 + col) * 64 + kk * 32 + hi * 8);
        const float* xp = xg + (size_t)blk * 1024 + col * 16;
        f32x4 P0[4], P1[4], P2[4];
#define XLOADQ(PA)                                                            \
        PA[0] = *(const f32x4*)(xp + 0);                                      \
        PA[1] = *(const f32x4*)(xp + 4);                                      \
        PA[2] = *(const f32x4*)(xp + 8);                                      \
        PA[3] = *(const f32x4*)(xp + 12);                                     \
        xp += 28672;
        XLOADQ(P0)
        XLOADQ(P1)
        XLOADQ(P2)

#define QA(PA, CUR, S)                                                        \
        {                                                                     \
            if ((S) < 75) {                                                   \
                half8 afr[2];                                                 \
                _Pragma("unroll") for (int kk = 0; kk < 2; ++kk)              \
                    afr[kk] = *(const half8*)&hb2[CUR][lr][kk * 32 + hi * 8]; \
                f32x4 aI = PA[0], aF = PA[1], aG4 = PA[2], aO = PA[3];        \
                XLOADQ(PA)                                                    \
                _Pragma("unroll") for (int kk = 0; kk < 2; ++kk) {            \
                    aI = __builtin_amdgcn_mfma_f32_16x16x32_f16(afr[kk], bw[0][kk], aI, 0, 0, 0);  \
                    aF = __builtin_amdgcn_mfma_f32_16x16x32_f16(afr[kk], bw[1][kk], aF, 0, 0, 0);  \
                    aG4 = __builtin_amdgcn_mfma_f32_16x16x32_f16(afr[kk], bw[2][kk], aG4, 0, 0, 0);\
                    aO = __builtin_amdgcn_mfma_f32_16x16x32_f16(afr[kk], bw[3][kk], aO, 0, 0, 0);  \
                }                                                             \
                ACT(aI, aF, aG4, aO)                                          \
                hb2[(CUR) ^ 1][hi][col] = hv;                                 \
                hp2[(CUR) ^ 1][hi][col] = hv;                                 \
            }                                                                 \
            FTAIL                                                             \
        }
        #pragma unroll 1
        for (int it = 0; it < 13; ++it) {
            const int b6 = it * 6;
            QA(P0, 0, b6 + 0) QA(P1, 1, b6 + 1) QA(P2, 0, b6 + 2)
            QA(P0, 1, b6 + 3) QA(P1, 0, b6 + 4) QA(P2, 1, b6 + 5)
        }
#undef QA
#undef XLOADQ
    } else if (w < 8) {  // ----- L3: H=64, HIN=64, lag 1 -----
        const int col = (w - 4) * 16 + (l & 15);
        half8 bwB[4][2], bwI[4][2];
        #pragma unroll
        for (int G = 0; G < 4; ++G)
            #pragma unroll
            for (int kk = 0; kk < 2; ++kk) {
                bwB[G][kk] = *(const half8*)(whh3 + (size_t)(G * 64 + col) * 64 + kk * 32 + hi * 8);
                bwI[G][kk] = *(const half8*)(wih3 + (size_t)(G * 64 + col) * 64 + kk * 32 + hi * 8);
            }
        const float bI = biasP[col], bF = biasP[64 + col];
        const float bG = biasP[128 + col], bO = biasP[192 + col];
        #pragma unroll 1
        for (int s = 0; s < 78; ++s) {
            const int cur = s & 1;
            if (s >= 1 && s <= 75) {
                half8 afr[2], air[2];
                #pragma unroll
                for (int kk = 0; kk < 2; ++kk) {
                    afr[kk] = *(const half8*)&hb3[cur][lr][kk * 32 + hi * 8];
                    air[kk] = *(const half8*)&hp2[cur][lr][kk * 32 + hi * 8];
                }
                f32x4 aI = {bI, bI, bI, bI}, aF = {bF, bF, bF, bF};
                f32x4 aG4 = {bG, bG, bG, bG}, aO = {bO, bO, bO, bO};
                #pragma unroll
                for (int kk = 0; kk < 2; ++kk) {
                    aI = __builtin_amdgcn_mfma_f32_16x16x32_f16(afr[kk], bwB[0][kk], aI, 0, 0, 0);
                    aF = __builtin_amdgcn_mfma_f32_16x16x32_f16(afr[kk], bwB[1][kk], aF, 0, 0, 0);
                    aG4 = __builtin_amdgcn_mfma_f32_16x16x32_f16(afr[kk], bwB[2][kk], aG4, 0, 0, 0);
                    aO = __builtin_amdgcn_mfma_f32_16x16x32_f16(afr[kk], bwB[3][kk], aO, 0, 0, 0);
                }
                #pragma unroll
                for (int kk = 0; kk < 2; ++kk) {
                    aI = __builtin_amdgcn_mfma_f32_16x16x32_f16(air[kk], bwI[0][kk], aI, 0, 0, 0);
                    aF = __builtin_amdgcn_mfma_f32_16x16x32_f16(air[kk], bwI[1][kk], aF, 0, 0, 0);
                    aG4 = __builtin_amdgcn_mfma_f32_16x16x32_f16(air[kk], bwI[2][kk], aG4, 0, 0, 0);
                    aO = __builtin_amdgcn_mfma_f32_16x16x32_f16(air[kk], bwI[3][kk], aO, 0, 0, 0);
                }
                ACT(aI, aF, aG4, aO)
                hb3[cur ^ 1][hi][col] = hv;
                hp3[cur ^ 1][hi][col] = hv;
            }
            FTAIL
        }
    } else if (w < 10) {  // ----- L4: H=32, HIN=64, lag 2 -----
        const int col = (w - 8) * 16 + (l & 15);
        half8 bwB[4], bwI[4][2];
        #pragma unroll
        for (int G = 0; G < 4; ++G) {
            bwB[G] = *(const half8*)(whh4 + (size_t)(G * 32 + col) * 32 + hi * 8);
            #pragma unroll
            for (int kk = 0; kk < 2; ++kk)
                bwI[G][kk] = *(const half8*)(wih4 + (size_t)(G * 32 + col) * 64 + kk * 32 + hi * 8);
        }
        const float* bp = biasP + 256;
        const float bI = bp[col], bF = bp[32 + col], bG = bp[64 + col], bO = bp[96 + col];
        #pragma unroll 1
        for (int s = 0; s < 78; ++s) {
            const int cur = s & 1;
            if (s >= 2 && s <= 76) {
                half8 afr = *(const half8*)&hb4[cur][lr][hi * 8];
                half8 air[2];
                #pragma unroll
                for (int kk = 0; kk < 2; ++kk)
                    air[kk] = *(const half8*)&hp3[cur][lr][kk * 32 + hi * 8];
                f32x4 aI = {bI, bI, bI, bI}, aF = {bF, bF, bF, bF};
                f32x4 aG4 = {bG, bG, bG, bG}, aO = {bO, bO, bO, bO};
                aI = __builtin_amdgcn_mfma_f32_16x16x32_f16(afr, bwB[0], aI, 0, 0, 0);
                aF = __builtin_amdgcn_mfma_f32_16x16x32_f16(afr, bwB[1], aF, 0, 0, 0);
                aG4 = __builtin_amdgcn_mfma_f32_16x16x32_f16(afr, bwB[2], aG4, 0, 0, 0);
                aO = __builtin_amdgcn_mfma_f32_16x16x32_f16(afr, bwB[3], aO, 0, 0, 0);
                #pragma unroll
                for (int kk = 0; kk < 2; ++kk) {
                    aI = __builtin_amdgcn_mfma_f32_16x16x32_f16(air[kk], bwI[0][kk], aI, 0, 0, 0);
                    aF = __builtin_amdgcn_mfma_f32_16x16x32_f16(air[kk], bwI[1][kk], aF, 0, 0, 0);
                    aG4 = __builtin_amdgcn_mfma_f32_16x16x32_f16(air[kk], bwI[2][kk], aG4, 0, 0, 0);
                    aO = __builtin_amdgcn_mfma_f32_16x16x32_f16(air[kk], bwI[3][kk], aO, 0, 0, 0);
                }
                ACT(aI, aF, aG4, aO)
                hb4[cur ^ 1][hi][col] = hv;
                hp4[cur ^ 1][hi][col] = hv;
            }
            FTAIL
        }
    } else {  // ----- L5: H=32, HIN=32, lag 3; writes h5 -----
        const int col = (w - 10) * 16 + (l & 15);
        half8 bwB[4], bwI[4];
        #pragma unroll
        for (int G = 0; G < 4; ++G) {
            bwB[G] = *(const half8*)(whh5 + (size_t)(G * 32 + col) * 32 + hi * 8);
            bwI[G] = *(const half8*)(wih5 + (size_t)(G * 32 + col) * 32 + hi * 8);
        }
        const float* bp = biasP + 384;
        const float bI = bp[col], bF = bp[32 + col], bG = bp[64 + col], bO = bp[96 + col];
        _Float16* hop = hout + (size_t)(blk * 4 + hi) * 32 + col;
        #pragma unroll 1
        for (int s = 0; s < 78; ++s) {
            const int cur = s & 1;
            if (s >= 3) {
                half8 afr = *(const half8*)&hb5[cur][lr][hi * 8];
                half8 air = *(const half8*)&hp4[cur][lr][hi * 8];
                f32x4 aI = {bI, bI, bI, bI}, aF = {bF, bF, bF, bF};
                f32x4 aG4 = {bG, bG, bG, bG}, aO = {bO, bO, bO, bO};
                aI = __builtin_amdgcn_mfma_f32_16x16x32_f16(afr, bwB[0], aI, 0, 0, 0);
                aF = __builtin_amdgcn_mfma_f32_16x16x32_f16(afr, bwB[1], aF, 0, 0, 0);
                aG4 = __builtin_amdgcn_mfma_f32_16x16x32_f16(afr, bwB[2], aG4, 0, 0, 0);
                aO = __builtin_amdgcn_mfma_f32_16x16x32_f16(afr, bwB[3], aO, 0, 0, 0);
                aI = __builtin_amdgcn_mfma_f32_16x16x32_f16(air, bwI[0], aI, 0, 0, 0);
                aF = __builtin_amdgcn_mfma_f32_16x16x32_f16(air, bwI[1], aF, 0, 0, 0);
                aG4 = __builtin_amdgcn_mfma_f32_16x16x32_f16(air, bwI[2], aG4, 0, 0, 0);
                aO = __builtin_amdgcn_mfma_f32_16x16x32_f16(air, bwI[3], aO, 0, 0, 0);
                ACT(aI, aF, aG4, aO)
                hb5[cur ^ 1][hi][col] = hv;
                *hop = hv;
                hop += 3584;
            }
            FTAIL
        }
    }
}

// ---------------------------------------------------------------------------
// Final linear: out[100][60] = h5 @ lin_w^T + lin_b; h5 is [75][112][32] fp16.
// ---------------------------------------------------------------------------
__global__ __launch_bounds__(256) void linear_out(
    const _Float16* __restrict__ h, const float* __restrict__ lw,
    const float* __restrict__ lb, float* __restrict__ out) {
    int wave = (blockIdx.x * 256 + threadIdx.x) >> 6;
    int l = threadIdx.x & 63;
    if (wave >= 6000) return;
    int b = wave / 60, o = wave - b * 60;
    int hc = l & 31, t0 = l >> 5;
    float acc = 0.f;
    for (int t = t0; t < 75; t += 2)
        acc += (float)h[((size_t)t * 112 + b) * 32 + hc] * lw[(size_t)o * 2400 + t * 32 + hc];
    #pragma unroll
    for (int s = 32; s; s >>= 1) acc += __shfl_xor(acc, s, 64);
    if (l == 0) out[b * 60 + o] = acc + lb[o];
}

// ---------------------------------------------------------------------------
extern "C" void kernel_launch(void* const* d_in, const int* in_sizes, int n_in,
                              void* d_out, int out_size, void* d_ws, size_t ws_size,
                              hipStream_t stream) {
    const float* x = (const float*)d_in[0];
    const float* wih[6];
    const float* whhp[6];
    const float* bih[6];
    const float* bhh[6];
    for (int i = 0; i < 6; ++i) {
        wih[i] = (const float*)d_in[1 + 4 * i];
        whhp[i] = (const float*)d_in[2 + 4 * i];
        bih[i] = (const float*)d_in[3 + 4 * i];
        bhh[i] = (const float*)d_in[4 + 4 * i];
    }
    const float* lw = (const float*)d_in[25];
    const float* lb = (const float*)d_in[26];
    float* out = (float*)d_out;

    char* ws = (char*)d_ws;
    size_t cur = 0;
    auto alloc = [&](size_t b) {
        size_t o = cur;
        cur += (b + 255) & ~(size_t)255;
        return o;
    };
    _Float16* x16 = (_Float16*)(ws + alloc((size_t)8448 * 76 * 2));
    _Float16* wihI0 = (_Float16*)(ws + alloc(38912 * 2));
    _Float16* wihI1 = (_Float16*)(ws + alloc(65536 * 2));
    _Float16* wihI2 = (_Float16*)(ws + alloc(32768 * 2));
    _Float16* wihP3 = (_Float16*)(ws + alloc(16384 * 2));
    _Float16* wihP4 = (_Float16*)(ws + alloc(8192 * 2));
    _Float16* wihP5 = (_Float16*)(ws + alloc(4096 * 2));
    _Float16* whhP[6];
    const size_t whhBytes[6] = {131072, 131072, 32768, 32768, 8192, 8192};
    for (int i = 0; i < 6; ++i) whhP[i] = (_Float16*)(ws + alloc(whhBytes[i]));
    float* biasI = (float*)(ws + alloc(1280 * 4));
    float* biasP = (float*)(ws + alloc(512 * 4));
    float* xg = (float*)(ws + alloc((size_t)78 * 28 * 512 * 4 * 4));
    _Float16* h0 = (_Float16*)(ws + alloc((size_t)75 * 112 * 128 * 2));
    _Float16* h1 = (_Float16*)(ws + alloc((size_t)75 * 112 * 128 * 2));
    _Float16* h5 = (_Float16*)(ws + alloc((size_t)75 * 112 * 32 * 2));

    PrepPtrs pp;
    for (int i = 0; i < 6; ++i) {
        pp.wih[i] = wih[i];
        pp.whh[i] = whhp[i];
        pp.bi[i] = bih[i];
        pp.bh[i] = bhh[i];
        pp.whhP[i] = whhP[i];
    }
    pp.x = x;
    pp.wihI0 = wihI0;
    pp.wihI1 = wihI1;
    pp.wihI2 = wihI2;
    pp.wihP3 = wihP3;
    pp.wihP4 = wihP4;
    pp.wihP5 = wihP5;
    pp.biasI = biasI;
    pp.biasP = biasP;
    pp.x16 = x16;
    prep_kernel<<<3835, 256, 0, stream>>>(pp);

    // layer 0: I=75 (Kv=76), H=128
    gemm_xg<3><<<dim3(150, 8), 256, 0, stream>>>(x16, wihI0, biasI + 0, xg, 76, 512);
    lstm_rec<128><<<25, 512, 0, stream>>>(xg, whhP[0], h0);
    // layer 1: I=128, H=128
    gemm_xg<4><<<dim3(150, 8), 256, 0, stream>>>(h0, wihI1, biasI + 512, xg, 128, 512);
    lstm_rec<128><<<25, 512, 0, stream>>>(xg, whhP[1], h1);
    // layer 2 xg GEMM (I=128, H=64), then quad-fused layers 2..5
    gemm_xg<4><<<dim3(150, 4), 256, 0, stream>>>(h1, wihI2, biasI + 1024, xg, 128, 256);
    lstm_quad<<<25, 768, 0, stream>>>(xg, whhP[2], whhP[3], wihP3, whhP[4],
                                      wihP4, whhP[5], wihP5, biasP, h5);

    linear_out<<<1500, 256, 0, stream>>>(h5, lw, lb, out);
}